// Round 14
// baseline (115.135 us; speedup 1.0000x reference)
//
#include <hip/hip_runtime.h>
#include <hip/hip_fp8.h>

#define NROWS 131072
#define NCLS  1000
#define CPAD  1024
#define DDIM  256

typedef __attribute__((ext_vector_type(4))) float f32x4;
typedef __attribute__((ext_vector_type(2))) long l64x2;

__device__ __forceinline__ float wred(float v){
#pragma unroll
  for (int m = 1; m < 64; m <<= 1) v += __shfl_xor(v, m, 64);
  return v;
}

__device__ __forceinline__ float fexp2(float x){
#if __has_builtin(__builtin_amdgcn_exp2f)
  return __builtin_amdgcn_exp2f(x);
#else
  float r; asm("v_exp_f32 %0, %1" : "=v"(r) : "v"(x)); return r;
#endif
}

// pack 4 f32 -> 4 fp8(e4m3) bytes in one uint (byte0=a .. byte3=d)
__device__ __forceinline__ unsigned pk4_fp8(float a, float b, float c, float d){
#if __has_builtin(__builtin_amdgcn_cvt_pk_fp8_f32)
  int v = __builtin_amdgcn_cvt_pk_fp8_f32(a, b, 0, false);
  v = __builtin_amdgcn_cvt_pk_fp8_f32(c, d, v, true);
  return (unsigned)v;
#else
  __hip_fp8_e4m3 fa(a), fb(b), fc(c), fd(d);
  return (unsigned)fa.__x | ((unsigned)fb.__x<<8) |
         ((unsigned)fc.__x<<16) | ((unsigned)fd.__x<<24);
#endif
}

// FP8 fragment-pair-linear layout for new_memory (B operand), 256 B/class:
// chunk ch = 32 cols (8 KB). For k=0..7 (K-step of 32), lane l=g*16+r16:
// 16 B at [ch*8192 + k*1024 + l*16] = frag(k,nb=0) (8 B: col r16, elems
// k*32+g*8..+8) followed by frag(k,nb=1) (col 16+r16). One dwordx4 per k.
__device__ __forceinline__ void store_frag8(unsigned char* nmem, int c, int ln,
                                            float a, float b, float x, float y){
  int ch = c >> 5, nb = (c >> 4) & 1, r16 = c & 15;
  int k = ln >> 3, g = (ln >> 1) & 3, q = ln & 1;
  *(unsigned*)(nmem + ch*8192 + k*1024 + (g*16+r16)*16 + nb*8 + q*4) =
      pk4_fp8(a, b, x, y);
}

// ---------------------------------------------------------------------------
// Kernel 1: 2 classes per block, 1024 threads (16 waves). Ballot-scan labels
// (int4 loads), gather matching rows coalesced, then the full
// batch_center -> update_wei -> new_memory chain in-block. Deterministic.
// Output written as FP8 in fragment-pair-linear order.
// ---------------------------------------------------------------------------
__global__ __launch_bounds__(1024) void k_center(
    const float* __restrict__ feat, const float* __restrict__ memory,
    const int* __restrict__ label, unsigned char* __restrict__ nmem){
  const int c0 = blockIdx.x * 2;
  const int t = threadIdx.x;
  const int w = t >> 6, lane = t & 63;
  if (c0 >= NCLS){                 // zero pad classes -> padded logits exactly 0
    if (t < 128) store_frag8(nmem, c0 + (t >> 6), t & 63, 0.f, 0.f, 0.f, 0.f);
    return;
  }
  const int c1 = c0 + 1;
  __shared__ float4 accred[2][16][64];
  __shared__ int cw[2][16];

  float4 a0 = make_float4(0.f,0.f,0.f,0.f);
  float4 a1 = make_float4(0.f,0.f,0.f,0.f);
  int cnt0 = 0, cnt1 = 0;
  const float4* feat4 = (const float4*)feat;
  const int4*   lab4  = (const int4*)label;

  for (int it = 0; it < 32; ++it){
    int base = (w*32 + it) * 256;              // wave w owns rows [w*8192, +8192)
    int4 lv = lab4[base/4 + lane];
#pragma unroll
    for (int sub = 0; sub < 4; ++sub){
      int lvv = (sub==0)?lv.x:(sub==1)?lv.y:(sub==2)?lv.z:lv.w;
      unsigned long long m0 = __ballot(lvv == c0);
      unsigned long long m1 = __ballot(lvv == c1);
      cnt0 += (int)__popcll(m0); cnt1 += (int)__popcll(m1);
      while (m0){
        int b = __ffsll((long long)m0) - 1; m0 &= m0 - 1;
        int r = base + b*4 + sub;
        float4 x = feat4[r*64 + lane];
        float ss = wred(x.x*x.x + x.y*x.y + x.z*x.z + x.w*x.w);
        float sc = 1.0f / fmaxf(sqrtf(ss), 1e-12f);
        a0.x += x.x*sc; a0.y += x.y*sc; a0.z += x.z*sc; a0.w += x.w*sc;
      }
      while (m1){
        int b = __ffsll((long long)m1) - 1; m1 &= m1 - 1;
        int r = base + b*4 + sub;
        float4 x = feat4[r*64 + lane];
        float ss = wred(x.x*x.x + x.y*x.y + x.z*x.z + x.w*x.w);
        float sc = 1.0f / fmaxf(sqrtf(ss), 1e-12f);
        a1.x += x.x*sc; a1.y += x.y*sc; a1.z += x.z*sc; a1.w += x.w*sc;
      }
    }
  }
  accred[0][w][lane] = a0; accred[1][w][lane] = a1;
  if (lane == 0){ cw[0][w] = cnt0; cw[1][w] = cnt1; }
  __syncthreads();

  if (t < 128){                     // wave 0 -> c0, wave 1 -> c1
    int cls = t >> 6, ln = t & 63;
    float sx=0.f, sy=0.f, sz=0.f, sw=0.f; int total = 0;
#pragma unroll
    for (int s = 0; s < 16; ++s){
      float4 v = accred[cls][s][ln];
      sx += v.x; sy += v.y; sz += v.z; sw += v.w;
      total += cw[cls][s];
    }
    int c = c0 + cls;
    float ss = wred(sx*sx + sy*sy + sz*sz + sw*sw);
    float inv = 1.0f / fmaxf(sqrtf(ss), 1e-12f);
    float bx = sx*inv, by = sy*inv, bz = sz*inv, bw = sw*inv;  // 0 if empty
    float flag = (total > 0) ? 1.0f : 0.0f;
    float4 m = ((const float4*)memory)[c*64 + ln];
    float simi = wred(m.x*bx + m.y*by + m.z*bz + m.w*bw);
    float wei = 1.0f - (1.0f - simi)*flag;
    float rx = wei*m.x + (1.0f-wei)*bx;
    float ry = wei*m.y + (1.0f-wei)*by;
    float rz = wei*m.z + (1.0f-wei)*bz;
    float rw = wei*m.w + (1.0f-wei)*bw;
    float ss2 = wred(rx*rx + ry*ry + rz*rz + rw*rw);
    float inv2 = 1.0f / fmaxf(sqrtf(ss2), 1e-12f);
    store_frag8(nmem, c, ln, rx*inv2, ry*inv2, rz*inv2, rw*inv2);
  }
}

// ---------------------------------------------------------------------------
// Kernel 2: fused GEMM + softmax-denominator + label-logit. LDS-FREE,
// BARRIER-FREE, FP8, 64 ROWS/WAVE (4 M-fragments):
//  2048 waves (was 4096) -> total L2 B-stream halves to 512 MB; MFMA and
//  total epilogue VALU invariant. VGPR ~200 -> exactly 2 waves/SIMD, which
//  is all the waves that exist (2048/1024). launch_bounds(256,2) caps VGPR
//  at 256 (no spill cliff). Register ping-pong prefetch per chunk:
//  MFMA(k0..3, bA) -> load bA<-next -> MFMA(k4..7, bB) -> load bB<-next ->
//  epilogue (32 outputs of compute cover). Per-block rotated chunk order.
//  1/||a||*log2e on logits in epilogue; base-2 exp; overwrite-select label
//  logit. Padded cols exact zeros -> exp2(0)=1: subtract 24.
// ---------------------------------------------------------------------------
#define MFMA8 __builtin_amdgcn_mfma_f32_16x16x32_fp8_fp8

__global__ __launch_bounds__(256, 2) void k_gemm(
    const float* __restrict__ feat, const unsigned char* __restrict__ nmem,
    const int* __restrict__ label, float* __restrict__ partials){
  __shared__ float bred[4];
  const int t = threadIdx.x, w = t >> 6, lane = t & 63;
  const int g = lane >> 4, r16 = lane & 15;
  const int rowbase = blockIdx.x * 256;

  // ---- A: global -> fp8 registers in fragment layout; sumsq on the fly
  long areg[4][8];
  float rs_self[4];
#pragma unroll
  for (int mf = 0; mf < 4; ++mf){
    int row = rowbase + w*64 + mf*16 + r16;
    const float4* rp = (const float4*)(feat + row*DDIM);
    float ss = 0.f;
#pragma unroll
    for (int kt = 0; kt < 8; ++kt){
      float4 x0 = rp[kt*8 + g*2];
      float4 x1 = rp[kt*8 + g*2 + 1];
      ss += x0.x*x0.x + x0.y*x0.y + x0.z*x0.z + x0.w*x0.w
          + x1.x*x1.x + x1.y*x1.y + x1.z*x1.z + x1.w*x1.w;
      unsigned lo = pk4_fp8(x0.x, x0.y, x0.z, x0.w);
      unsigned hi = pk4_fp8(x1.x, x1.y, x1.z, x1.w);
      areg[mf][kt] = (long)(((unsigned long)hi << 32) | lo);
    }
    ss += __shfl_xor(ss, 16, 64);    // lanes l, l^16, l^32, l^48 share a row
    ss += __shfl_xor(ss, 32, 64);
    rs_self[mf] = 1.0f / fmaxf(sqrtf(ss), 1e-12f);
  }

  int labreg[4][4];
  float rs2[4][4];                   // inv-norm * log2e for epilogue rows
#pragma unroll
  for (int m = 0; m < 4; ++m)
#pragma unroll
    for (int j = 0; j < 4; ++j){
      int rr = w*64 + m*16 + g*4 + j;       // C-frag row of acc[m][*][j]
      labreg[m][j] = label[rowbase + rr];
      rs2[m][j] = __shfl(rs_self[m], g*4 + j, 16) * 1.44269504f;
    }

  float esum[4][4], slb[4][4];
#pragma unroll
  for (int m = 0; m < 4; ++m)
#pragma unroll
    for (int j = 0; j < 4; ++j){ esum[m][j] = 0.f; slb[m][j] = 0.f; }

  const char* nbp = (const char*)nmem + lane*16;
  const int rot = blockIdx.x & 31;         // per-block chunk rotation
  long bA[8], bB[8];                       // frag(k,nb): k=0..3 / k=4..7

#define LOADLO(CH)                                                            \
  { const char* cb = nbp + (size_t)(CH)*8192;                                 \
    _Pragma("unroll")                                                         \
    for (int k2 = 0; k2 < 4; ++k2){                                           \
      l64x2 v = *(const l64x2*)(cb + k2*1024);                                \
      bA[k2*2] = v.x; bA[k2*2+1] = v.y; } }
#define LOADHI(CH)                                                            \
  { const char* cb = nbp + (size_t)(CH)*8192 + 4096;                          \
    _Pragma("unroll")                                                         \
    for (int k2 = 0; k2 < 4; ++k2){                                           \
      l64x2 v = *(const l64x2*)(cb + k2*1024);                                \
      bB[k2*2] = v.x; bB[k2*2+1] = v.y; } }

  LOADLO(rot); LOADHI(rot);

  for (int it = 0; it < 32; ++it){
    int cur = (it + rot) & 31;
    int nxt = (it + 1 + rot) & 31;

    f32x4 acc[4][2];
    __builtin_amdgcn_s_setprio(1);
    {   // k=0: init accs from bA
      f32x4 Z = {0.f,0.f,0.f,0.f};
#pragma unroll
      for (int m = 0; m < 4; ++m){
        acc[m][0] = MFMA8(areg[m][0], bA[0], Z, 0, 0, 0);
        acc[m][1] = MFMA8(areg[m][0], bA[1], Z, 0, 0, 0);
      }
    }
#pragma unroll
    for (int k = 1; k < 4; ++k)
#pragma unroll
      for (int m = 0; m < 4; ++m){
        acc[m][0] = MFMA8(areg[m][k], bA[k*2+0], acc[m][0], 0, 0, 0);
        acc[m][1] = MFMA8(areg[m][k], bA[k*2+1], acc[m][1], 0, 0, 0);
      }
    __builtin_amdgcn_s_setprio(0);

    if (it < 31) LOADLO(nxt);        // bA free; loads fly under bB-phase+epi

    __builtin_amdgcn_s_setprio(1);
#pragma unroll
    for (int k = 4; k < 8; ++k)
#pragma unroll
      for (int m = 0; m < 4; ++m){
        acc[m][0] = MFMA8(areg[m][k], bB[(k-4)*2+0], acc[m][0], 0, 0, 0);
        acc[m][1] = MFMA8(areg[m][k], bB[(k-4)*2+1], acc[m][1], 0, 0, 0);
      }
    __builtin_amdgcn_s_setprio(0);

    if (it < 31) LOADHI(nxt);        // bB free; loads fly under epilogue

    // ---- epilogue: scale (inv-norm * log2e), exp2-accumulate, label select
#pragma unroll
    for (int m = 0; m < 4; ++m)
#pragma unroll
      for (int n = 0; n < 2; ++n){
        int col = cur*32 + n*16 + r16;
#pragma unroll
        for (int j = 0; j < 4; ++j){
          float v = acc[m][n][j] * rs2[m][j];
          esum[m][j] += fexp2(v);
          slb[m][j] = (col == labreg[m][j]) ? v : slb[m][j];
        }
      }
  }

  // ---- final: reduce 16-lane groups once, per-block loss partial
  float v = 0.f;
#pragma unroll
  for (int m = 0; m < 4; ++m)
#pragma unroll
    for (int j = 0; j < 4; ++j){
      float e = esum[m][j], s = slb[m][j];
      e += __shfl_xor(e, 1, 64); e += __shfl_xor(e, 2, 64);
      e += __shfl_xor(e, 4, 64); e += __shfl_xor(e, 8, 64);
      s += __shfl_xor(s, 1, 64); s += __shfl_xor(s, 2, 64);
      s += __shfl_xor(s, 4, 64); s += __shfl_xor(s, 8, 64);
      // 24 padded cols contribute exp2(0)=1 each; slb/log are base-2 -> *ln2
      v += 0.69314718056f * (__log2f(e - 24.0f) - s);
    }
  if (r16 != 0) v = 0.f;               // one lane per 16-lane row-group
  v = wred(v);
  if (lane == 0) bred[w] = v;
  __syncthreads();
  if (t == 0) partials[blockIdx.x] = bred[0] + bred[1] + bred[2] + bred[3];
}

// ---------------------------------------------------------------------------
// Kernel 3: reduce 512 block partials -> mean loss (deterministic order)
// ---------------------------------------------------------------------------
__global__ __launch_bounds__(256) void k_final(
    const float* __restrict__ partials, float* __restrict__ out){
  const int t = threadIdx.x;
  const int w = t >> 6, lane = t & 63;
  __shared__ float red[4];
  float s = partials[t] + partials[t+256];
  s = wred(s);
  if (lane == 0) red[w] = s;
  __syncthreads();
  if (t == 0) out[0] = (red[0]+red[1]+red[2]+red[3]) * (1.0f/(float)NROWS);
}

// ---------------------------------------------------------------------------
// ws layout: [0, 262144) new_memory fp8 (fragment-pair-linear, 1024x256),
//            [524288, +2048) partials
// ---------------------------------------------------------------------------
extern "C" void kernel_launch(void* const* d_in, const int* in_sizes, int n_in,
                              void* d_out, int out_size, void* d_ws, size_t ws_size,
                              hipStream_t stream){
  const float* feat   = (const float*)d_in[0];
  const float* memory = (const float*)d_in[1];
  const int*   label  = (const int*)d_in[2];
  float* out = (float*)d_out;
  unsigned char* nmem = (unsigned char*)d_ws;
  float* partials = (float*)((char*)d_ws + 524288);

  k_center<<<CPAD/2, 1024, 0, stream>>>(feat, memory, label, nmem);
  k_gemm<<<NROWS/256, 256, 0, stream>>>(feat, nmem, label, partials);
  k_final<<<1, 256, 0, stream>>>(partials, out);
}

// Round 15
// 108.925 us; speedup vs baseline: 1.0570x; 1.0570x over previous
//
#include <hip/hip_runtime.h>
#include <hip/hip_fp8.h>

#define NROWS 131072
#define NCLS  1000
#define CPAD  1024
#define DDIM  256

typedef __attribute__((ext_vector_type(4))) float f32x4;
typedef __attribute__((ext_vector_type(2))) long l64x2;

__device__ __forceinline__ float wred(float v){
#pragma unroll
  for (int m = 1; m < 64; m <<= 1) v += __shfl_xor(v, m, 64);
  return v;
}

__device__ __forceinline__ float fexp2(float x){
#if __has_builtin(__builtin_amdgcn_exp2f)
  return __builtin_amdgcn_exp2f(x);
#else
  float r; asm("v_exp_f32 %0, %1" : "=v"(r) : "v"(x)); return r;
#endif
}

// pack 4 f32 -> 4 fp8(e4m3) bytes in one uint (byte0=a .. byte3=d)
__device__ __forceinline__ unsigned pk4_fp8(float a, float b, float c, float d){
#if __has_builtin(__builtin_amdgcn_cvt_pk_fp8_f32)
  int v = __builtin_amdgcn_cvt_pk_fp8_f32(a, b, 0, false);
  v = __builtin_amdgcn_cvt_pk_fp8_f32(c, d, v, true);
  return (unsigned)v;
#else
  __hip_fp8_e4m3 fa(a), fb(b), fc(c), fd(d);
  return (unsigned)fa.__x | ((unsigned)fb.__x<<8) |
         ((unsigned)fc.__x<<16) | ((unsigned)fd.__x<<24);
#endif
}

// FP8 fragment-pair-linear layout for new_memory (B operand), 256 B/class:
// chunk ch = 32 cols (8 KB). For k=0..7 (K-step of 32), lane l=g*16+r16:
// 16 B at [ch*8192 + k*1024 + l*16] = frag(k,nb=0) then frag(k,nb=1).
__device__ __forceinline__ void store_frag8(unsigned char* nmem, int c, int ln,
                                            float a, float b, float x, float y){
  int ch = c >> 5, nb = (c >> 4) & 1, r16 = c & 15;
  int k = ln >> 3, g = (ln >> 1) & 3, q = ln & 1;
  *(unsigned*)(nmem + ch*8192 + k*1024 + (g*16+r16)*16 + nb*8 + q*4) =
      pk4_fp8(a, b, x, y);
}

// ---------------------------------------------------------------------------
// Kernel 1: 2 classes per block, 1024 threads (16 waves). Ballot-scan labels
// (int4 loads), gather matching rows coalesced, then the full
// batch_center -> update_wei -> new_memory chain in-block. Deterministic.
// Output written as FP8 in fragment-pair-linear order.
// ---------------------------------------------------------------------------
__global__ __launch_bounds__(1024) void k_center(
    const float* __restrict__ feat, const float* __restrict__ memory,
    const int* __restrict__ label, unsigned char* __restrict__ nmem){
  const int c0 = blockIdx.x * 2;
  const int t = threadIdx.x;
  const int w = t >> 6, lane = t & 63;
  if (c0 >= NCLS){                 // zero pad classes -> padded logits exactly 0
    if (t < 128) store_frag8(nmem, c0 + (t >> 6), t & 63, 0.f, 0.f, 0.f, 0.f);
    return;
  }
  const int c1 = c0 + 1;
  __shared__ float4 accred[2][16][64];
  __shared__ int cw[2][16];

  float4 a0 = make_float4(0.f,0.f,0.f,0.f);
  float4 a1 = make_float4(0.f,0.f,0.f,0.f);
  int cnt0 = 0, cnt1 = 0;
  const float4* feat4 = (const float4*)feat;
  const int4*   lab4  = (const int4*)label;

  for (int it = 0; it < 32; ++it){
    int base = (w*32 + it) * 256;              // wave w owns rows [w*8192, +8192)
    int4 lv = lab4[base/4 + lane];
#pragma unroll
    for (int sub = 0; sub < 4; ++sub){
      int lvv = (sub==0)?lv.x:(sub==1)?lv.y:(sub==2)?lv.z:lv.w;
      unsigned long long m0 = __ballot(lvv == c0);
      unsigned long long m1 = __ballot(lvv == c1);
      cnt0 += (int)__popcll(m0); cnt1 += (int)__popcll(m1);
      while (m0){
        int b = __ffsll((long long)m0) - 1; m0 &= m0 - 1;
        int r = base + b*4 + sub;
        float4 x = feat4[r*64 + lane];
        float ss = wred(x.x*x.x + x.y*x.y + x.z*x.z + x.w*x.w);
        float sc = 1.0f / fmaxf(sqrtf(ss), 1e-12f);
        a0.x += x.x*sc; a0.y += x.y*sc; a0.z += x.z*sc; a0.w += x.w*sc;
      }
      while (m1){
        int b = __ffsll((long long)m1) - 1; m1 &= m1 - 1;
        int r = base + b*4 + sub;
        float4 x = feat4[r*64 + lane];
        float ss = wred(x.x*x.x + x.y*x.y + x.z*x.z + x.w*x.w);
        float sc = 1.0f / fmaxf(sqrtf(ss), 1e-12f);
        a1.x += x.x*sc; a1.y += x.y*sc; a1.z += x.z*sc; a1.w += x.w*sc;
      }
    }
  }
  accred[0][w][lane] = a0; accred[1][w][lane] = a1;
  if (lane == 0){ cw[0][w] = cnt0; cw[1][w] = cnt1; }
  __syncthreads();

  if (t < 128){                     // wave 0 -> c0, wave 1 -> c1
    int cls = t >> 6, ln = t & 63;
    float sx=0.f, sy=0.f, sz=0.f, sw=0.f; int total = 0;
#pragma unroll
    for (int s = 0; s < 16; ++s){
      float4 v = accred[cls][s][ln];
      sx += v.x; sy += v.y; sz += v.z; sw += v.w;
      total += cw[cls][s];
    }
    int c = c0 + cls;
    float ss = wred(sx*sx + sy*sy + sz*sz + sw*sw);
    float inv = 1.0f / fmaxf(sqrtf(ss), 1e-12f);
    float bx = sx*inv, by = sy*inv, bz = sz*inv, bw = sw*inv;  // 0 if empty
    float flag = (total > 0) ? 1.0f : 0.0f;
    float4 m = ((const float4*)memory)[c*64 + ln];
    float simi = wred(m.x*bx + m.y*by + m.z*bz + m.w*bw);
    float wei = 1.0f - (1.0f - simi)*flag;
    float rx = wei*m.x + (1.0f-wei)*bx;
    float ry = wei*m.y + (1.0f-wei)*by;
    float rz = wei*m.z + (1.0f-wei)*bz;
    float rw = wei*m.w + (1.0f-wei)*bw;
    float ss2 = wred(rx*rx + ry*ry + rz*rz + rw*rw);
    float inv2 = 1.0f / fmaxf(sqrtf(ss2), 1e-12f);
    store_frag8(nmem, c, ln, rx*inv2, ry*inv2, rz*inv2, rw*inv2);
  }
}

// ---------------------------------------------------------------------------
// Kernel 2: fused GEMM + softmax-denominator + label-logit. LDS-FREE,
// BARRIER-FREE, FP8, 64 rows/wave + acc PING-PONG (T15):
//  While chunk ch's 64 MFMAs issue into accA, the epilogue of ch-1 runs from
//  accB, textually interleaved one 4-output EPI slice per 8-MFMA k-group
//  (setprio removed: it fences the compiler scheduler). The row scale
//  (1/||a||)*log2e is folded into the A fp8 pack, so the MFMA output IS the
//  base-2 logit: epilogue = exp2 + add + cmp + sel only. Label compare vs
//  wave-uniform scalar via labc = label - r16. B register ping-pong + block
//  chunk rotation as before. Padded cols exact zeros -> exp2(0)=1 each:
//  subtract 24 from the denominator.
// ---------------------------------------------------------------------------
#define MFMA8 __builtin_amdgcn_mfma_f32_16x16x32_fp8_fp8

__global__ __launch_bounds__(256, 2) void k_gemm(
    const float* __restrict__ feat, const unsigned char* __restrict__ nmem,
    const int* __restrict__ label, float* __restrict__ partials){
  __shared__ float bred[4];
  const int t = threadIdx.x, w = t >> 6, lane = t & 63;
  const int g = lane >> 4, r16 = lane & 15;
  const int rowbase = blockIdx.x * 256;

  // ---- A: load row fragment, norm, fold (1/||a||)*log2e into fp8 pack
  long areg[4][8];
#pragma unroll
  for (int mf = 0; mf < 4; ++mf){
    int row = rowbase + w*64 + mf*16 + r16;
    const float4* rp = (const float4*)(feat + row*DDIM);
    float4 xv[16];
    float ss = 0.f;
#pragma unroll
    for (int kt = 0; kt < 8; ++kt){
      xv[kt*2]   = rp[kt*8 + g*2];
      xv[kt*2+1] = rp[kt*8 + g*2 + 1];
      float4 x0 = xv[kt*2], x1 = xv[kt*2+1];
      ss += x0.x*x0.x + x0.y*x0.y + x0.z*x0.z + x0.w*x0.w
          + x1.x*x1.x + x1.y*x1.y + x1.z*x1.z + x1.w*x1.w;
    }
    ss += __shfl_xor(ss, 16, 64);    // lanes l, l^16, l^32, l^48 share a row
    ss += __shfl_xor(ss, 32, 64);
    float sc = 1.44269504f / fmaxf(sqrtf(ss), 1e-12f);
#pragma unroll
    for (int kt = 0; kt < 8; ++kt){
      float4 x0 = xv[kt*2], x1 = xv[kt*2+1];
      unsigned lo = pk4_fp8(x0.x*sc, x0.y*sc, x0.z*sc, x0.w*sc);
      unsigned hi = pk4_fp8(x1.x*sc, x1.y*sc, x1.z*sc, x1.w*sc);
      areg[mf][kt] = (long)(((unsigned long)hi << 32) | lo);
    }
  }

  int labc[4][4];                    // label - r16 (compare vs scalar col)
#pragma unroll
  for (int m = 0; m < 4; ++m)
#pragma unroll
    for (int j = 0; j < 4; ++j)
      labc[m][j] = label[rowbase + w*64 + m*16 + g*4 + j] - r16;

  float esum[4][4], slb[4][4];
#pragma unroll
  for (int m = 0; m < 4; ++m)
#pragma unroll
    for (int j = 0; j < 4; ++j){ esum[m][j] = 0.f; slb[m][j] = 0.f; }

  const char* nbp = (const char*)nmem + lane*16;
  const int rot = blockIdx.x & 31;         // per-block chunk rotation
  long bA[8], bB[8];                       // frag(k,nb): k=0..3 / k=4..7
  f32x4 accA[4][2], accB[4][2];

#define LOADLO(CH)                                                            \
  { const char* cb = nbp + (size_t)(CH)*8192;                                 \
    _Pragma("unroll")                                                         \
    for (int k2 = 0; k2 < 4; ++k2){                                           \
      l64x2 v = *(const l64x2*)(cb + k2*1024);                                \
      bA[k2*2] = v.x; bA[k2*2+1] = v.y; } }
#define LOADHI(CH)                                                            \
  { const char* cb = nbp + (size_t)(CH)*8192 + 4096;                          \
    _Pragma("unroll")                                                         \
    for (int k2 = 0; k2 < 4; ++k2){                                           \
      l64x2 v = *(const l64x2*)(cb + k2*1024);                                \
      bB[k2*2] = v.x; bB[k2*2+1] = v.y; } }

  // epilogue slice S (4 of 32 outputs) of acc P; COLS0 = chunk*32 (uniform)
#define EPI_SLICE(P, COLS0, S)                                                \
  { const int m_ = (S) >> 1, n_ = (S) & 1;                                    \
    int cols_ = (COLS0) + n_*16;                                              \
    _Pragma("unroll")                                                         \
    for (int j = 0; j < 4; ++j){                                              \
      float v_ = P[m_][n_][j];                                                \
      esum[m_][j] += fexp2(v_);                                               \
      slb[m_][j] = (cols_ == labc[m_][j]) ? v_ : slb[m_][j];                  \
    } }

  // one chunk: MFMAs into ACC, interleaved with EPI slices of PRV (prev acc)
#define CHUNK(ACC, PRV, PCOLS, NXT, DOLD, DOEPI)                              \
  {                                                                           \
    { f32x4 Z = {0.f,0.f,0.f,0.f};                                            \
      _Pragma("unroll")                                                       \
      for (int m = 0; m < 4; ++m){                                            \
        ACC[m][0] = MFMA8(areg[m][0], bA[0], Z, 0, 0, 0);                     \
        ACC[m][1] = MFMA8(areg[m][0], bA[1], Z, 0, 0, 0); } }                 \
    if (DOEPI) EPI_SLICE(PRV, PCOLS, 0);                                      \
    _Pragma("unroll")                                                         \
    for (int k = 1; k < 4; ++k){                                              \
      _Pragma("unroll")                                                       \
      for (int m = 0; m < 4; ++m){                                            \
        ACC[m][0] = MFMA8(areg[m][k], bA[k*2+0], ACC[m][0], 0, 0, 0);         \
        ACC[m][1] = MFMA8(areg[m][k], bA[k*2+1], ACC[m][1], 0, 0, 0); }       \
      if (DOEPI) EPI_SLICE(PRV, PCOLS, k);                                    \
    }                                                                         \
    if (DOLD) LOADLO(NXT);                                                    \
    _Pragma("unroll")                                                         \
    for (int k = 4; k < 8; ++k){                                              \
      _Pragma("unroll")                                                       \
      for (int m = 0; m < 4; ++m){                                            \
        ACC[m][0] = MFMA8(areg[m][k], bB[(k-4)*2+0], ACC[m][0], 0, 0, 0);     \
        ACC[m][1] = MFMA8(areg[m][k], bB[(k-4)*2+1], ACC[m][1], 0, 0, 0); }   \
      if (DOEPI) EPI_SLICE(PRV, PCOLS, k);                                    \
    }                                                                         \
    if (DOLD) LOADHI(NXT);                                                    \
  }

  LOADLO(rot); LOADHI(rot);

  // it 0: chunk c(0) -> accA, no previous epilogue
  CHUNK(accA, accB, 0, (rot+1)&31, true, false);

  for (int p = 0; p < 15; ++p){
    int cB = (2*p   + rot) & 31;   // chunk finished in accA (epi during it 2p+1)
    int nB = (2*p+2 + rot) & 31;
    CHUNK(accB, accA, cB*32, nB, true, true);
    int cA = (2*p+1 + rot) & 31;   // chunk finished in accB (epi during it 2p+2)
    int nA = (2*p+3 + rot) & 31;
    CHUNK(accA, accB, cA*32, nA, true, true);
  }
  // it 31: chunk c(31) -> accB, epilogue of c(30) from accA, no loads
  CHUNK(accB, accA, ((30+rot)&31)*32, 0, false, true);
  {
    int cc = ((31+rot)&31)*32;
#pragma unroll
    for (int s = 0; s < 8; ++s) EPI_SLICE(accB, cc, s);
  }

  // ---- final: reduce 16-lane groups once, per-block loss partial
  float v = 0.f;
#pragma unroll
  for (int m = 0; m < 4; ++m)
#pragma unroll
    for (int j = 0; j < 4; ++j){
      float e = esum[m][j], s = slb[m][j];
      e += __shfl_xor(e, 1, 64); e += __shfl_xor(e, 2, 64);
      e += __shfl_xor(e, 4, 64); e += __shfl_xor(e, 8, 64);
      s += __shfl_xor(s, 1, 64); s += __shfl_xor(s, 2, 64);
      s += __shfl_xor(s, 4, 64); s += __shfl_xor(s, 8, 64);
      // 24 padded cols contribute exp2(0)=1 each; slb/log are base-2 -> *ln2
      v += 0.69314718056f * (__log2f(e - 24.0f) - s);
    }
  if (r16 != 0) v = 0.f;               // one lane per 16-lane row-group
  v = wred(v);
  if (lane == 0) bred[w] = v;
  __syncthreads();
  if (t == 0) partials[blockIdx.x] = bred[0] + bred[1] + bred[2] + bred[3];
}

// ---------------------------------------------------------------------------
// Kernel 3: reduce 512 block partials -> mean loss (deterministic order)
// ---------------------------------------------------------------------------
__global__ __launch_bounds__(256) void k_final(
    const float* __restrict__ partials, float* __restrict__ out){
  const int t = threadIdx.x;
  const int w = t >> 6, lane = t & 63;
  __shared__ float red[4];
  float s = partials[t] + partials[t+256];
  s = wred(s);
  if (lane == 0) red[w] = s;
  __syncthreads();
  if (t == 0) out[0] = (red[0]+red[1]+red[2]+red[3]) * (1.0f/(float)NROWS);
}

// ---------------------------------------------------------------------------
// ws layout: [0, 262144) new_memory fp8 (fragment-pair-linear, 1024x256),
//            [524288, +2048) partials
// ---------------------------------------------------------------------------
extern "C" void kernel_launch(void* const* d_in, const int* in_sizes, int n_in,
                              void* d_out, int out_size, void* d_ws, size_t ws_size,
                              hipStream_t stream){
  const float* feat   = (const float*)d_in[0];
  const float* memory = (const float*)d_in[1];
  const int*   label  = (const int*)d_in[2];
  float* out = (float*)d_out;
  unsigned char* nmem = (unsigned char*)d_ws;
  float* partials = (float*)((char*)d_ws + 524288);

  k_center<<<CPAD/2, 1024, 0, stream>>>(feat, memory, label, nmem);
  k_gemm<<<NROWS/256, 256, 0, stream>>>(feat, nmem, label, partials);
  k_final<<<1, 256, 0, stream>>>(partials, out);
}